// Round 15
// baseline (2091.332 us; speedup 1.0000x reference)
//
#include <hip/hip_runtime.h>

typedef __attribute__((ext_vector_type(8))) short bf16x8;
typedef __attribute__((ext_vector_type(4))) float f32x4;
typedef unsigned short ushort_t;
typedef unsigned int uint_t;
typedef __attribute__((address_space(3))) uint_t lds_u32;
typedef const __attribute__((address_space(1))) uint_t glb_u32;

__device__ __forceinline__ float b2f(ushort_t h){ uint_t u = ((uint_t)h)<<16; float f; __builtin_memcpy(&f,&u,4); return f; }
__device__ __forceinline__ ushort_t f2b(float f){ uint_t u; __builtin_memcpy(&u,&f,4); uint_t r = (u + 0x7fffu + ((u>>16)&1u))>>16; return (ushort_t)r; }
__device__ __forceinline__ float as_f(float v){ return v; }
__device__ __forceinline__ float as_f(ushort_t v){ return b2f(v); }
__device__ __forceinline__ int iclamp(int v, int lo, int hi){ return v < lo ? lo : (v > hi ? hi : v); }
__device__ __forceinline__ void gld16(const void* g, void* l){
  __builtin_amdgcn_global_load_lds((glb_u32*)g, (lds_u32*)l, 16, 0, 0);
}

// ---------------- generalized tiled+pre-swizzled weight repack (T=1 weights) ----------------
// layout [t][mb][c][row128][kb64]; stored = w[m=mb*128+row][k=c*64+(kb^((row&7)<<3))][t]; 0-padded
__global__ __launch_bounds__(256) void repack_at_k(const float* __restrict__ w, ushort_t* __restrict__ o,
                                                   int Co, int Ci, int T, int Mb, int Kc){
  long total = (long)T*Mb*Kc*8192;
  long i = (long)blockIdx.x*256 + threadIdx.x;
  if (i >= total) return;
  int e  = (int)(i & 8191);
  long j = i >> 13;
  int c  = (int)(j % Kc); j /= Kc;
  int mb = (int)(j % Mb);
  int t  = (int)(j / Mb);
  int row = e >> 6, kb = e & 63;
  int m = mb*128 + row;
  int k = c*64 + (kb ^ ((row&7)<<3));
  float v = (m < Co && k < Ci) ? w[((size_t)m*Ci + k)*T + t] : 0.f;
  o[i] = f2b(v);
}

// 9-tap repack: one thread handles all 9 taps of one (mb,c,row,kb) slot.
__global__ __launch_bounds__(256) void repack9_k(const float* __restrict__ w, ushort_t* __restrict__ o,
                                                 int Ci, int Kc){
  long total = (long)2*Kc*8192;
  long i = (long)blockIdx.x*256 + threadIdx.x;
  if (i >= total) return;
  int e  = (int)(i & 8191);
  long j = i >> 13;
  int c  = (int)(j % Kc);
  int mb = (int)(j / Kc);
  int row = e >> 6, kb = e & 63;
  int m = mb*128 + row;
  int k = c*64 + (kb ^ ((row&7)<<3));
  size_t tapstride = (size_t)2*Kc*8192;
  if (k < Ci){
    const float* src = w + ((size_t)m*Ci + k)*9;
    #pragma unroll
    for (int t=0;t<9;t++) o[(size_t)t*tapstride + i] = f2b(src[t]);
  } else {
    #pragma unroll
    for (int t=0;t<9;t++) o[(size_t)t*tapstride + i] = 0;
  }
}

// xm split-bf16 weights: taps {hi, hi, lo} of w_max [256][2048]
__global__ __launch_bounds__(256) void repack_xm_k(const float* __restrict__ w, ushort_t* __restrict__ o){
  long i = (long)blockIdx.x*256 + threadIdx.x;
  if (i >= 3l*2*32*8192) return;
  int e  = (int)(i & 8191);
  long j = i >> 13;
  int c  = (int)(j & 31);
  long j2 = j >> 5;
  int mb = (int)(j2 & 1);
  int t  = (int)(j2 >> 1);
  int row = e >> 6, kb = e & 63;
  int m = mb*128 + row;
  int k = c*64 + (kb ^ ((row&7)<<3));
  float v = w[(size_t)m*2048 + k];
  ushort_t hi = f2b(v);
  o[i] = (t < 2) ? hi : f2b(v - b2f(hi));
}

// identity BN slice (for r4 channels 1024..1279 in stats1536)
__global__ void id_stats_k(float* __restrict__ s){
  int c = threadIdx.x;
  s[(1024+c)*2] = 0.f; s[(1024+c)*2+1] = 1.f;
}

// identity fill for stats320 channels 48..319 (upsample output already post-BN; pad cols x zero weights)
__global__ void id_stats320_k(float* __restrict__ s){
  for (int c = 48 + threadIdx.x; c < 320; c += 256){
    s[c*2] = 0.f; s[c*2+1] = 1.f;
  }
}

// ---------------- NCHW f32 -> NHWC bf16 (tiled transpose; optional lo-part, k-swizzle, pool partials) ----
__global__ __launch_bounds__(256) void to_nhwc_k(const float* __restrict__ in, ushort_t* __restrict__ hi,
                                                 ushort_t* __restrict__ lo, float* __restrict__ ppart,
                                                 int C, int HW, int ldo, int swz){
  __shared__ float t[64][65];
  int p0 = blockIdx.x*64, c0 = blockIdx.y*64, n = blockIdx.z;
  const float* src = in + (size_t)n*C*HW;
  int tp = threadIdx.x & 63, tr = threadIdx.x >> 6;
  #pragma unroll
  for (int i=0;i<16;i++){ int c = tr + i*4; t[c][tp] = src[(size_t)(c0+c)*HW + p0 + tp]; }
  __syncthreads();
  size_t nbase = (size_t)n*HW*ldo;
  float ssum = 0.f;
  #pragma unroll
  for (int i=0;i<16;i++){
    int pr = tr + i*4;
    int p  = p0 + pr;
    int cc = c0 + (swz ? (tp ^ ((p&7)<<3)) : tp);
    float v = t[tp][pr];
    ssum += v;
    ushort_t h = f2b(v);
    hi[nbase + (size_t)p*ldo + cc] = h;
    if (lo) lo[nbase + (size_t)p*ldo + cc] = f2b(v - b2f(h));
  }
  if (ppart){
    __syncthreads();
    t[tr][tp] = ssum;
    __syncthreads();
    if (tr == 0){
      float s = t[0][tp] + t[1][tp] + t[2][tp] + t[3][tp];
      ppart[((size_t)(n*gridDim.x + blockIdx.x))*C + c0 + tp] = s;
    }
  }
}

__global__ __launch_bounds__(256) void pool_fin_k(const float* __restrict__ ppart, float* __restrict__ pooled){
  int gid = blockIdx.x*256 + threadIdx.x;   // 16384 = 8*2048
  int n = gid >> 11, c = gid & 2047;
  float s = 0.f;
  for (int pb=0; pb<64; pb++) s += ppart[((size_t)(n*64 + pb))*2048 + c];
  pooled[gid] = s*(1.f/4096.f);
}

// ---------------- batched ASPP conv: z=0 (1x1), z=1..3 (3x3 d12/24/36), z=4 (xm split-bf16, fp32 out) ----
// R13 structure (tap-outer, k-inner): R14's k-outer reorder regressed (L2 window 32 blocks x 144KB > 4MB).
// Block-uniform zero-tap skip retained (bit-identical).
__global__ __launch_bounds__(256, 4) void aspp_conv(const ushort_t* __restrict__ Aall,
                                                 const ushort_t* __restrict__ B,
                                                 const ushort_t* __restrict__ Blo,
                                                 ushort_t* __restrict__ cat,
                                                 float* __restrict__ XM,
                                                 float* __restrict__ catpart,
                                                 float* __restrict__ xmpart){
  __shared__ __align__(16) ushort_t As[128*64];
  __shared__ __align__(16) ushort_t Bs[128*64];
  const int tid = threadIdx.x;
  const int lane = tid & 63, wave = tid >> 6;
  const int wm = (wave>>1)*64, wn = (wave&1)*64;
  const int r = lane & 15, g = lane >> 4;
  const int m0 = blockIdx.y * 128;
  const int xt = blockIdx.x;
  const int p0 = (((xt&7)<<5) | (xt>>3)) << 7;   // XCD-chunked
  const int z  = blockIdx.z;
  const int ntap = (z==0) ? 1 : (z==4 ? 3 : 9);
  const int dil  = (z>=1 && z<=3) ? 12*z : 0;
  const int tap0 = (z==0) ? 0 : (z==4 ? 28 : 1 + 9*(z-1));
  const bool lin = (z==0) || (z==4);
  const int y0blk = (p0 & 4095) >> 6;           // block spans rows y0blk, y0blk+1
  const int srow0 = tid >> 3;
  const int scb16 = (tid & 7) * 16;
  const int swz_s = (srow0 & 7) << 4;

  f32x4 acc[4][4];
  #pragma unroll
  for (int i=0;i<4;i++){
    #pragma unroll
    for (int j=0;j<4;j++){ f32x4 zz = {0.f,0.f,0.f,0.f}; acc[i][j] = zz; }
  }

  for (int t=0; t<ntap; ++t){
    int dy=0, dx=0;
    if (ntap==9){
      dy = (t/3 - 1)*dil; dx = (t%3 - 1)*dil;
      // block-uniform: skip taps whose y-range is entirely OOB (exact-zero contribution)
      if (y0blk + 1 + dy < 0 || y0blk + dy > 63) continue;
    }
    const ushort_t* Bt = (z==4 && t==1) ? Blo : B;
    for (int k0=0; k0<2048; k0+=64){
      const int c = k0 >> 6;
      {
        const char* gA = (const char*)Aall + ((((size_t)(tap0+t)*2 + (m0>>7))*32 + c)<<14) + wave*1024 + lane*16;
        char* lA = (char*)As + wave*1024;
        gld16(gA,          lA);
        gld16(gA +  4096,  lA +  4096);
        gld16(gA +  8192,  lA +  8192);
        gld16(gA + 12288,  lA + 12288);
      }
      if (lin){
        const char* gB = (const char*)Bt + ((size_t)(p0 + wave*8 + (lane>>3))<<12) + (c<<7) + ((lane&7)<<4);
        char* lB = (char*)Bs + wave*1024;
        gld16(gB,                     lB);
        gld16(gB + (size_t)32*4096,   lB +  4096);
        gld16(gB + (size_t)64*4096,   lB +  8192);
        gld16(gB + (size_t)96*4096,   lB + 12288);
      } else {
        #pragma unroll
        for (int i=0;i<4;i+=2){
          uint4 v0{}, v1{};
          #pragma unroll
          for (int u=0;u<2;u++){
            int row = srow0 + (i+u)*32;
            int p = p0 + row;
            int sp = p & 4095;
            int yy = (sp >> 6) + dy, xx = (sp & 63) + dx;
            if ((uint_t)yy < 64u && (uint_t)xx < 64u){
              int q = ((p >> 12) << 12) | (yy << 6) | xx;
              uint4 vv = *(const uint4*)((const char*)B + ((size_t)q<<12) + (c<<7) + (scb16 ^ ((q&7)<<4)));
              if (u==0) v0 = vv; else v1 = vv;
            }
          }
          *(uint4*)((char*)Bs + (srow0+i*32)*128 + (scb16 ^ swz_s)) = v0;
          *(uint4*)((char*)Bs + (srow0+(i+1)*32)*128 + (scb16 ^ swz_s)) = v1;
        }
      }
      __syncthreads();
      #pragma unroll
      for (int ks=0; ks<2; ++ks){
        bf16x8 av[4], bv[4];
        #pragma unroll
        for (int mf=0; mf<4; ++mf){
          int row = wm + mf*16 + r;
          av[mf] = *(const bf16x8*)((const char*)As + row*128 + (((ks*64) + g*16) ^ ((row&7)<<4)));
        }
        #pragma unroll
        for (int nf=0; nf<4; ++nf){
          int row = wn + nf*16 + r;
          bv[nf] = *(const bf16x8*)((const char*)Bs + row*128 + (((ks*64) + g*16) ^ ((row&7)<<4)));
        }
        #pragma unroll
        for (int mf=0; mf<4; ++mf){
          #pragma unroll
          for (int nf=0; nf<4; ++nf)
            acc[mf][nf] = __builtin_amdgcn_mfma_f32_16x16x32_bf16(av[mf], bv[nf], acc[mf][nf], 0,0,0);
        }
      }
      __syncthreads();
    }
  }
  // BN partials from fp32 acc; slot = xt*2 + (wave&1)
  float* part = (z==4) ? xmpart : catpart;
  int cbase = (z==4) ? 0 : z*256;
  int slot = xt*2 + (wave&1);
  #pragma unroll
  for (int mf=0; mf<4; ++mf){
    float ps[4], pss[4];
    #pragma unroll
    for (int j=0;j<4;j++){ ps[j]=0.f; pss[j]=0.f; }
    #pragma unroll
    for (int nf=0; nf<4; ++nf){
      #pragma unroll
      for (int j=0;j<4;j++){ float v = acc[mf][nf][j]; ps[j]+=v; pss[j]+=v*v; }
    }
    #pragma unroll
    for (int o=8;o;o>>=1){
      #pragma unroll
      for (int j=0;j<4;j++){ ps[j]+=__shfl_xor(ps[j],o,16); pss[j]+=__shfl_xor(pss[j],o,16); }
    }
    if (r==0){
      int co = m0 + wm + mf*16 + g*4;
      #pragma unroll
      for (int j=0;j<4;j++){
        size_t idx = ((size_t)(cbase + co + j)*512 + slot)*2;
        part[idx] = ps[j]; part[idx+1] = pss[j];
      }
    }
  }
  if (z == 4){
    #pragma unroll
    for (int mf=0; mf<4; ++mf){
      int co = m0 + wm + mf*16 + g*4;
      #pragma unroll
      for (int nf=0; nf<4; ++nf){
        int pos = p0 + wn + nf*16 + r;
        *(f32x4*)(XM + (size_t)pos*256 + co) = acc[mf][nf];
      }
    }
  } else {
    ushort_t* Cout = cat + z*256;
    #pragma unroll
    for (int mf=0; mf<4; ++mf){
      int co = m0 + wm + mf*16 + g*4;
      #pragma unroll
      for (int nf=0; nf<4; ++nf){
        int pos = p0 + wn + nf*16 + r;
        ushort4 o;
        o.x = f2b(acc[mf][nf][0]); o.y = f2b(acc[mf][nf][1]);
        o.z = f2b(acc[mf][nf][2]); o.w = f2b(acc[mf][nf][3]);
        *(ushort4*)(Cout + (size_t)pos*1536 + co) = o;
      }
    }
  }
}

// ---------------- A-tiled implicit-GEMM conv (async A staging; B natural reg-staged) ----------------
// BN_B: apply per-channel bn_relu to B elements at load time (in-bounds only; OOB stays exact zero,
// matching reference zero-padding of the post-bn_relu tensor).
template<bool BN_B>
__global__ __launch_bounds__(256, 4) void gemm_conv_at(const ushort_t* __restrict__ At, const ushort_t* __restrict__ B,
               ushort_t* __restrict__ C,
               int Mvalid, int Mb, int Kc, int ldb, int ldc,
               int logW, int logHW, int H, int ntap, int dil,
               float* __restrict__ bnpart, int gridX, const float* __restrict__ bnB)
{
  __shared__ __align__(16) ushort_t As[128*64];
  __shared__ __align__(16) ushort_t Bs[128*64];
  const int tid = threadIdx.x;
  const int lane = tid & 63, wave = tid >> 6;
  const int wm = (wave>>1)*64, wn = (wave&1)*64;
  const int r = lane & 15, g = lane >> 4;
  const int mb = blockIdx.y;
  const int m0 = mb * 128;
  const int nx = (int)gridDim.x;
  const int xt = (int)blockIdx.x;
  const int p0 = (((nx & 7) == 0) ? ((xt&7)*(nx>>3) + (xt>>3)) : xt) * 128;
  const int W = 1<<logW, HWm1 = (1<<logHW)-1, Wm1 = W-1;
  const int yb0 = (p0 & HWm1) >> logW;
  const int yb1 = ((p0 & HWm1) + 127) >> logW;
  const int srow0 = tid >> 3;
  const int scb16 = (tid & 7) * 16;
  const int swz_s = (srow0 & 7) << 4;

  f32x4 acc[4][4];
  #pragma unroll
  for (int i=0;i<4;i++){
    #pragma unroll
    for (int j=0;j<4;j++){ f32x4 z = {0.f,0.f,0.f,0.f}; acc[i][j] = z; }
  }

  for (int t=0; t<ntap; ++t){
    int dy=0, dx=0;
    if (ntap==9){
      dy = (t/3 - 1)*dil; dx = (t%3 - 1)*dil;
      if (yb1 + dy < 0 || yb0 + dy >= H) continue;   // block-uniform zero-tap skip
    }
    for (int c=0; c<Kc; ++c){
      {
        const char* gA = (const char*)At + ((((size_t)t*Mb + mb)*Kc + c)<<14) + wave*1024 + lane*16;
        char* lA = (char*)As + wave*1024;
        gld16(gA,          lA);
        gld16(gA +  4096,  lA +  4096);
        gld16(gA +  8192,  lA +  8192);
        gld16(gA + 12288,  lA + 12288);
      }
      #pragma unroll
      for (int i=0;i<4;i+=2){
        uint4 v0{}, v1{};
        #pragma unroll
        for (int u=0;u<2;u++){
          int row = srow0 + (i+u)*32;
          int p = p0 + row;
          int sp = p & HWm1;
          int yy = (sp >> logW) + dy, xx = (sp & Wm1) + dx;
          if ((uint_t)yy < (uint_t)H && (uint_t)xx < (uint_t)W){
            int q = ((p >> logHW) << logHW) | (yy << logW) | xx;
            uint4 vv = *(const uint4*)(B + (size_t)q*ldb + (c*64 + (scb16>>1)));
            if constexpr (BN_B){
              union {uint4 q; ushort_t u[8];} uu; uu.q = vv;
              #pragma unroll
              for (int jj=0;jj<8;jj++){
                int ch = c*64 + (scb16>>1) + jj;
                float mm = bnB[ch*2], rr = bnB[ch*2+1];
                uu.u[jj] = f2b(fmaxf((b2f(uu.u[jj])-mm)*rr, 0.f));
              }
              vv = uu.q;
            }
            if (u==0) v0 = vv; else v1 = vv;
          }
        }
        *(uint4*)((char*)Bs + (srow0+i*32)*128 + (scb16 ^ swz_s)) = v0;
        *(uint4*)((char*)Bs + (srow0+(i+1)*32)*128 + (scb16 ^ swz_s)) = v1;
      }
      __syncthreads();
      #pragma unroll
      for (int ks=0; ks<2; ++ks){
        bf16x8 av[4], bv[4];
        #pragma unroll
        for (int mf=0; mf<4; ++mf){
          int row = wm + mf*16 + r;
          av[mf] = *(const bf16x8*)((const char*)As + row*128 + (((ks*64) + g*16) ^ ((row&7)<<4)));
        }
        #pragma unroll
        for (int nf=0; nf<4; ++nf){
          int row = wn + nf*16 + r;
          bv[nf] = *(const bf16x8*)((const char*)Bs + row*128 + (((ks*64) + g*16) ^ ((row&7)<<4)));
        }
        #pragma unroll
        for (int mf=0; mf<4; ++mf){
          #pragma unroll
          for (int nf=0; nf<4; ++nf)
            acc[mf][nf] = __builtin_amdgcn_mfma_f32_16x16x32_bf16(av[mf], bv[nf], acc[mf][nf], 0,0,0);
        }
      }
      __syncthreads();
    }
  }
  if (bnpart){
    int slot = xt*2 + (wave&1);
    #pragma unroll
    for (int mf=0; mf<4; ++mf){
      float ps[4], pss[4];
      #pragma unroll
      for (int j=0;j<4;j++){ ps[j]=0.f; pss[j]=0.f; }
      #pragma unroll
      for (int nf=0; nf<4; ++nf){
        #pragma unroll
        for (int j=0;j<4;j++){ float v = acc[mf][nf][j]; ps[j]+=v; pss[j]+=v*v; }
      }
      #pragma unroll
      for (int o=8;o;o>>=1){
        #pragma unroll
        for (int j=0;j<4;j++){ ps[j]+=__shfl_xor(ps[j],o,16); pss[j]+=__shfl_xor(pss[j],o,16); }
      }
      if (r==0){
        int co = m0 + wm + mf*16 + g*4;
        if (co < Mvalid){
          #pragma unroll
          for (int j=0;j<4;j++){
            size_t idx = ((size_t)(co + j)*(2*gridX) + slot)*2;
            bnpart[idx] = ps[j]; bnpart[idx+1] = pss[j];
          }
        }
      }
    }
  }
  #pragma unroll
  for (int mf=0; mf<4; ++mf){
    int co = m0 + wm + mf*16 + g*4;
    if (co >= Mvalid) continue;
    #pragma unroll
    for (int nf=0; nf<4; ++nf){
      int pos = p0 + wn + nf*16 + r;
      ushort4 o;
      o.x = f2b(acc[mf][nf][0]); o.y = f2b(acc[mf][nf][1]);
      o.z = f2b(acc[mf][nf][2]); o.w = f2b(acc[mf][nf][3]);
      *(ushort4*)(C + (size_t)pos*ldc + co) = o;
    }
  }
}

// ---------------- fp32 SGEMM fallback for w_max conv ----------------
__global__ __launch_bounds__(256) void sgemm_max(const float* __restrict__ Wt, const float* __restrict__ X,
                                                 float* __restrict__ C){
  __shared__ __align__(16) float As[32*68];
  __shared__ __align__(16) float Bs[32*64];
  int tid = threadIdx.x;
  int tx = tid & 15, ty = tid >> 4;
  int p0 = blockIdx.x * 64;
  int m0 = blockIdx.y * 64;
  int n  = blockIdx.z;
  const float* Xb = X + (size_t)n * 2048 * 4096;
  float acc[4][4];
  #pragma unroll
  for (int i=0;i<4;i++){
    #pragma unroll
    for (int j=0;j<4;j++) acc[i][j]=0.f;
  }
  for (int k0=0; k0<2048; k0+=32){
    #pragma unroll
    for (int i=0;i<8;i++){
      int idx = i*256 + tid;
      int mm = idx >> 5, kk = idx & 31;
      As[kk*68 + mm] = Wt[(size_t)(m0+mm)*2048 + k0 + kk];
    }
    #pragma unroll
    for (int i=0;i<8;i++){
      int idx = i*256 + tid;
      int kk = idx >> 6, pp = idx & 63;
      Bs[kk*64 + pp] = Xb[(size_t)(k0+kk)*4096 + p0 + pp];
    }
    __syncthreads();
    #pragma unroll
    for (int kk=0; kk<32; ++kk){
      f32x4 a = *(const f32x4*)&As[kk*68 + ty*4];
      f32x4 b = *(const f32x4*)&Bs[kk*64 + tx*4];
      #pragma unroll
      for (int i=0;i<4;i++){
        #pragma unroll
        for (int j=0;j<4;j++) acc[i][j] += a[i]*b[j];
      }
    }
    __syncthreads();
  }
  #pragma unroll
  for (int j=0;j<4;j++){
    f32x4 o = {acc[0][j], acc[1][j], acc[2][j], acc[3][j]};
    *(f32x4*)(C + (size_t)(n*4096 + p0 + tx*4 + j)*256 + m0 + ty*4) = o;
  }
}

// ---------------- r4: conv_pool + bn_relu over batch, one block per channel ----------------
__global__ __launch_bounds__(256) void r4_k(const float* __restrict__ pooled, const float* __restrict__ wpool,
                                            float* __restrict__ r4b){
  __shared__ float red[8][256];
  int co = blockIdx.x, t = threadIdx.x;
  float y[8];
  #pragma unroll
  for (int n=0;n<8;n++) y[n]=0.f;
  for (int ci=t; ci<2048; ci+=256){
    float wv = wpool[(size_t)co*2048+ci];
    #pragma unroll
    for (int n=0;n<8;n++) y[n] += pooled[n*2048+ci]*wv;
  }
  #pragma unroll
  for (int n=0;n<8;n++) red[n][t] = y[n];
  __syncthreads();
  for (int o=128;o;o>>=1){
    if (t<o){
      #pragma unroll
      for (int n=0;n<8;n++) red[n][t]+=red[n][t+o];
    }
    __syncthreads();
  }
  if (t==0){
    float yv[8], m=0.f;
    #pragma unroll
    for (int n=0;n<8;n++){ yv[n]=red[n][0]; m+=yv[n]; }
    m *= 0.125f;
    float v=0.f;
    #pragma unroll
    for (int n=0;n<8;n++){ float d=yv[n]-m; v+=d*d; }
    v *= 0.125f;
    float rs = rsqrtf(v + 1e-5f);
    #pragma unroll
    for (int n=0;n<8;n++) r4b[n*256+co] = fmaxf((yv[n]-m)*rs, 0.f);
  }
}

__global__ __launch_bounds__(256) void bcast_r4_k(const float* __restrict__ r4b, ushort_t* __restrict__ cat){
  int gid = blockIdx.x*256 + threadIdx.x;
  int pos = gid >> 5, cb = (gid & 31)*8;
  int n = pos >> 12;
  union {uint4 q; ushort_t u[8];} o;
  #pragma unroll
  for (int k=0;k<8;k++) o.u[k] = f2b(r4b[n*256 + cb + k]);
  *(uint4*)(cat + (size_t)pos*1536 + 1024 + cb) = o.q;
}

// ---------------- BN finalize from channel-major partials [C][NBp][2] ----------------
__global__ __launch_bounds__(256) void bn_fin2_k(const float* __restrict__ part, float* __restrict__ stats,
                                                 int NBp, float invN){
  __shared__ float rs_[256], rss_[256];
  int c = blockIdx.x, b = threadIdx.x;
  float s=0.f, ss=0.f;
  for (int e=b; e<NBp; e+=256){
    s  += part[((size_t)c*NBp+e)*2];
    ss += part[((size_t)c*NBp+e)*2+1];
  }
  rs_[b]=s; rss_[b]=ss;
  __syncthreads();
  for (int o=128;o;o>>=1){
    if (b<o){ rs_[b]+=rs_[b+o]; rss_[b]+=rss_[b+o]; }
    __syncthreads();
  }
  if (b==0){
    float m = rs_[0]*invN, var = rss_[0]*invN - m*m;
    stats[c*2]=m; stats[c*2+1]=rsqrtf(fmaxf(var,0.f)+1e-5f);
  }
}

// legacy partial/fin (fallback xm path only)
template<typename TIN>
__global__ __launch_bounds__(256) void bn_partial_k(const TIN* __restrict__ in, float* __restrict__ partial,
                                                    int P, int C, int ld){
  int b = blockIdx.x;
  for (int c = threadIdx.x; c < C; c += 256){
    float s=0.f, ss=0.f;
    for (int p=b; p<P; p+=gridDim.x){ float v = as_f(in[(size_t)p*ld+c]); s+=v; ss+=v*v; }
    partial[((size_t)b*C+c)*2]   = s;
    partial[((size_t)b*C+c)*2+1] = ss;
  }
}
__global__ __launch_bounds__(256) void bn_fin_k(const float* __restrict__ partial, float* __restrict__ stats,
                                                int C, float invN){
  __shared__ float rs_[256], rss_[256];
  int c = blockIdx.x, b = threadIdx.x;
  rs_[b]  = partial[((size_t)b*C+c)*2];
  rss_[b] = partial[((size_t)b*C+c)*2+1];
  __syncthreads();
  for (int o=128;o;o>>=1){
    if (b<o){ rs_[b]+=rs_[b+o]; rss_[b]+=rss_[b+o]; }
    __syncthreads();
  }
  if (b==0){
    float m = rs_[0]*invN, var = rss_[0]*invN - m*m;
    stats[c*2]=m; stats[c*2+1]=rsqrtf(fmaxf(var,0.f)+1e-5f);
  }
}

template<typename TIN>
__global__ __launch_bounds__(256) void bn_apply_k(const TIN* __restrict__ in, ushort_t* __restrict__ out,
                           const float* __restrict__ stats, int total8, int C8, int ldi, int ldo){
  int j = blockIdx.x*256 + threadIdx.x;
  if (j >= total8) return;
  int p = j / C8;
  int c0 = (j - p*C8)*8;
  float v[8];
  if constexpr (sizeof(TIN)==2){
    union { uint4 q; ushort_t u[8]; } ld;
    ld.q = *(const uint4*)((const ushort_t*)in + (size_t)p*ldi + c0);
    #pragma unroll
    for (int k=0;k<8;k++) v[k] = b2f(ld.u[k]);
  } else {
    const f32x4* s = (const f32x4*)((const float*)in + (size_t)p*ldi + c0);
    f32x4 a = s[0], b = s[1];
    #pragma unroll
    for (int k=0;k<4;k++){ v[k]=a[k]; v[k+4]=b[k]; }
  }
  union { ushort_t u[8]; uint4 q; } pk;
  #pragma unroll
  for (int k=0;k<8;k++){
    float m = stats[(c0+k)*2], rs = stats[(c0+k)*2+1];
    pk.u[k] = f2b(fmaxf((v[k]-m)*rs, 0.f));
  }
  *(uint4*)(out + (size_t)p*ldo + c0) = pk.q;
}

// ---------------- fused xm finish: bn_relu apply -> xm_bn (bf16) + channel-sum partials ----------------
__global__ __launch_bounds__(256) void xm_finish_k(const float* __restrict__ xm_raw, const float* __restrict__ stats,
                                                   ushort_t* __restrict__ xm_bn, float* __restrict__ partial, int P){
  int c = threadIdx.x, b = blockIdx.x;
  float m = stats[c*2], rs = stats[c*2+1];
  float s = 0.f;
  for (int p=b; p<P; p+=gridDim.x){
    float v = fmaxf((xm_raw[(size_t)p*256 + c] - m)*rs, 0.f);
    xm_bn[(size_t)p*256 + c] = f2b(v);
    s += v;
  }
  partial[(size_t)b*256 + c] = s;
}

__global__ __launch_bounds__(256) void chsum_fin_k(const float* __restrict__ partial, float* __restrict__ chs){
  __shared__ float r_[256];
  int c = blockIdx.x, b = threadIdx.x;
  r_[b] = partial[(size_t)b*256 + c];
  __syncthreads();
  for (int o=128;o;o>>=1){
    if (b<o) r_[b]+=r_[b+o];
    __syncthreads();
  }
  if (b==0) chs[c] = r_[0];
}

// ---------------- PSO (exact reference semantics, 1 wave, lanes = dims, chs in LDS) ----------------
__global__ void pso_k(const float* __restrict__ chs, const int* __restrict__ initp,
                      const float* __restrict__ rands, int* __restrict__ best){
  __shared__ float cl[256];
  int d = threadIdx.x;
  for (int i=d; i<256; i+=64) cl[i] = chs[i];
  __syncthreads();
  bool act = d < 9;
  float p[9], vel[9], bp[9], bs[9];
  #pragma unroll
  for (int i=0;i<9;i++){
    p[i] = act ? (float)initp[i*9+d] : 0.f;
    vel[i]=0.f; bp[i]=p[i];
  }
  #pragma unroll
  for (int i=0;i<9;i++){
    float s = act ? cl[(int)floorf(p[i])] : 0.f;
    for (int o=8;o;o>>=1) s += __shfl_xor(s,o,16);
    bs[i]=s;
  }
  float gs = bs[0]; int gi=0;
  #pragma unroll
  for (int i=1;i<9;i++) if (bs[i]<gs){gs=bs[i];gi=i;}
  float g = p[0];
  #pragma unroll
  for (int i=1;i<9;i++) if (i==gi) g = p[i];
  for (int it=0; it<100; ++it){
    #pragma unroll
    for (int i=0;i<9;i++){
      float r1 = rands[(it*9+i)*2], r2 = rands[(it*9+i)*2+1];
      float v = 0.7f*vel[i] + 1.5f*r1*(bp[i]-p[i]) + 1.5f*r2*(g-p[i]);
      float pn = fminf(fmaxf(p[i]+v, 0.f), 255.f);
      float fit = act ? cl[(int)floorf(pn)] : 0.f;
      for (int o=8;o;o>>=1) fit += __shfl_xor(fit,o,16);
      bool better = fit < bs[i];
      bp[i] = better ? pn : bp[i];
      bs[i] = better ? fit : bs[i];
      bool gb = fit < gs;
      g  = gb ? pn : g;
      gs = gb ? fit : gs;
      p[i]=pn; vel[i]=v;
    }
  }
  if (act) best[d] = (int)floorf(g);
}

// ---------------- x_sel gather + 1x1 conv (9 -> 256) -> cat slice 5 (+ BN partials) ----------------
__global__ __launch_bounds__(256) void sel_k(const ushort_t* __restrict__ xm_bn, const int* __restrict__ best,
        const float* __restrict__ wsel, ushort_t* __restrict__ cat, float* __restrict__ selpart){
  __shared__ float wl[2304];
  __shared__ float xv[8][9];
  int tid = threadIdx.x;
  for (int i=tid; i<2304; i+=256) wl[i] = wsel[i];
  if (tid < 72){
    int pp = tid/9, jj = tid - pp*9;
    int ch = best[jj];
    xv[pp][jj] = b2f(xm_bn[(size_t)(blockIdx.x*8 + pp)*256 + ch]);
  }
  __syncthreads();
  int co = tid;
  float s = 0.f, ss = 0.f;
  #pragma unroll
  for (int pp=0; pp<8; ++pp){
    float a = 0.f;
    #pragma unroll
    for (int j=0;j<9;j++) a += xv[pp][j]*wl[co*9+j];
    s += a; ss += a*a;
    cat[(size_t)(blockIdx.x*8+pp)*1536 + 1280 + co] = f2b(a);
  }
  size_t idx = ((size_t)co*4096 + blockIdx.x)*2;
  selpart[idx] = s; selpart[idx+1] = ss;
}

// ---------------- bilinear 2x upsample with fused BN+ReLU on sampled values ----------------
__global__ __launch_bounds__(256) void upsample_k(const ushort_t* __restrict__ aspp, const float* __restrict__ stats,
                                                  ushort_t* __restrict__ dst){
  int gid = blockIdx.x*256 + threadIdx.x;
  int pos = gid >> 5, c0 = (gid & 31)*8;
  int n = pos >> 14, sp = pos & 16383;
  int y = sp >> 7, x = sp & 127;
  float sy = y*0.5f - 0.25f, sx = x*0.5f - 0.25f;
  float fy = sy - floorf(sy), fx = sx - floorf(sx);
  int y0 = (int)floorf(sy), x0 = (int)floorf(sx);
  int ya = iclamp(y0,0,63),   yb = iclamp(y0+1,0,63);
  int xa = iclamp(x0,0,63),   xb = iclamp(x0+1,0,63);
  const ushort_t* base = aspp + ((size_t)n<<12)*256;
  float w00=(1.f-fy)*(1.f-fx), w01=(1.f-fy)*fx, w10=fy*(1.f-fx), w11=fy*fx;
  union {uint4 q; ushort_t u[8];} aa, ab, ba, bb, o;
  aa.q = *(const uint4*)(base + (size_t)(ya*64+xa)*256 + c0);
  ab.q = *(const uint4*)(base + (size_t)(ya*64+xb)*256 + c0);
  ba.q = *(const uint4*)(base + (size_t)(yb*64+xa)*256 + c0);
  bb.q = *(const uint4*)(base + (size_t)(yb*64+xb)*256 + c0);
  #pragma unroll
  for (int k=0;k<8;k++){
    float m = stats[(c0+k)*2], rs = stats[(c0+k)*2+1];
    float va = fmaxf((b2f(aa.u[k])-m)*rs, 0.f);
    float vb = fmaxf((b2f(ab.u[k])-m)*rs, 0.f);
    float vc = fmaxf((b2f(ba.u[k])-m)*rs, 0.f);
    float vd = fmaxf((b2f(bb.u[k])-m)*rs, 0.f);
    o.u[k] = f2b(w00*va + w01*vb + w10*vc + w11*vd);
  }
  *(uint4*)(dst + (size_t)pos*320 + 48 + c0) = o.q;
}

// ---------------- final 1x1 conv 256->21 + bias, fused BN+ReLU on h, write NCHW f32 ----------------
__global__ __launch_bounds__(256) void cls2_k(const ushort_t* __restrict__ h, const float* __restrict__ stats,
                                              const float* __restrict__ w,
                                              const float* __restrict__ bias, float* __restrict__ out){
  __shared__ float wl[5376];
  for (int idx=threadIdx.x; idx<5376; idx+=256) wl[idx]=w[idx];
  __syncthreads();
  int pos = blockIdx.x*256 + threadIdx.x;
  int n = pos >> 14, sp = pos & 16383;
  const ushort_t* hr = h + (size_t)pos*256;
  float acc[21];
  #pragma unroll
  for (int co=0;co<21;co++) acc[co]=bias[co];
  for (int k0=0;k0<256;k0+=8){
    union {uint4 q; ushort_t u[8];} ld;
    ld.q = *(const uint4*)(hr + k0);
    float f[8];
    #pragma unroll
    for (int j=0;j<8;j++){
      float m = stats[(k0+j)*2], rs = stats[(k0+j)*2+1];
      f[j] = fmaxf((b2f(ld.u[j])-m)*rs, 0.f);
    }
    #pragma unroll
    for (int co=0;co<21;co++){
      float s=acc[co];
      #pragma unroll
      for (int j=0;j<8;j++) s += f[j]*wl[co*256+k0+j];
      acc[co]=s;
    }
  }
  float* ob = out + (size_t)n*21*16384 + sp;
  #pragma unroll
  for (int co=0;co<21;co++) ob[(size_t)co*16384] = acc[co];
}

extern "C" void kernel_launch(void* const* d_in, const int* in_sizes, int n_in,
                              void* d_out, int out_size, void* d_ws, size_t ws_size,
                              hipStream_t stream) {
  (void)in_sizes; (void)n_in;
  const float* f_out  = (const float*)d_in[0];
  const float* f_low  = (const float*)d_in[1];
  const float* w_low  = (const float*)d_in[2];
  const float* w_a0   = (const float*)d_in[3];
  const float* w_a1   = (const float*)d_in[4];
  const float* w_a2   = (const float*)d_in[5];
  const float* w_a3   = (const float*)d_in[6];
  const float* w_pool = (const float*)d_in[7];
  const float* w_max  = (const float*)d_in[8];
  const float* w_sel  = (const float*)d_in[9];
  const float* w_proj = (const float*)d_in[10];
  const float* w_cls1 = (const float*)d_in[11];
  const float* w_cls2 = (const float*)d_in[12];
  const float* b_cls2 = (const float*)d_in[13];
  const float* rands  = (const float*)d_in[14];
  const int*   initp  = (const int*)d_in[15];
  float* outp = (float*)d_out;

  char* wsp = (char*)d_ws;
  auto alloc = [&](size_t bytes)->char*{ char* p = wsp; wsp += (bytes + 255) & ~(size_t)255; return p; };
  ushort_t* xb      = (ushort_t*)alloc((size_t)8*4096*2048*2);   // feature_out NHWC bf16 (pre-swizzled k)
  ushort_t* lowb    = (ushort_t*)alloc((size_t)131072*256*2);    // feature_low NHWC bf16; later aliased as h
  ushort_t* cls1in  = (ushort_t*)alloc((size_t)131072*320*2);    // [low(48) RAW | up(256) post-BN | zpad(16)]
  ushort_t* cat     = (ushort_t*)alloc((size_t)32768*1536*2);    // r0..r5 NHWC (RAW; BN fused into proj load)
  float*    xm_raw  = (float*)alloc((size_t)32768*256*4);
  ushort_t* xm_bn   = (ushort_t*)alloc((size_t)32768*256*2);
  ushort_t* aspp    = (ushort_t*)alloc((size_t)32768*256*2);     // RAW; BN fused into upsample
  ushort_t* wr_aspp = (ushort_t*)alloc((size_t)31*524288*2);     // tiled swizzled: a0|a1[9]|a2[9]|a3[9]|xm[3]
  ushort_t* wr_low  = (ushort_t*)alloc((size_t)1*1*4*8192*2);
  ushort_t* wr_proj = (ushort_t*)alloc((size_t)1*2*24*8192*2);
  ushort_t* wr_cls1 = (ushort_t*)alloc((size_t)9*2*5*8192*2);
  float*    pooled  = (float*)alloc((size_t)16384*4);
  float*    ppart   = (float*)alloc((size_t)8*64*2048*4);
  float*    r4b     = (float*)alloc((size_t)2048*4);
  float*    catpart = (float*)alloc((size_t)1024*512*2*4);
  float*    xmpart  = (float*)alloc((size_t)256*512*2*4);
  float*    hpart   = (float*)alloc((size_t)256*2048*2*4);
  float*    lowpart = (float*)alloc((size_t)128*2048*2*4);
  float*    projpart= (float*)alloc((size_t)256*512*2*4);
  float*    selpart = (float*)alloc((size_t)256*4096*2*4);
  float*    partial = (float*)alloc((size_t)256*256*2*4);
  float*    stats1536=(float*)alloc((size_t)1536*2*4);           // [statsA | id(r4) | statsS]
  float*    statsX  = (float*)alloc((size_t)256*2*4);
  float*    statsP  = (float*)alloc((size_t)256*2*4);
  float*    stats320= (float*)alloc((size_t)320*2*4);            // [statsL(48) | id(272)] for cls1 B-load
  float*    statsH  = (float*)alloc((size_t)256*2*4);
  float*    chs     = (float*)alloc((size_t)256*4);
  int*      best    = (int*)alloc(64);
  size_t need_base = (size_t)(wsp - (char*)d_ws);
  ushort_t* xb_lo   = (ushort_t*)alloc((size_t)8*4096*2048*2);   // lo part for split-bf16 xm
  size_t need_full = (size_t)(wsp - (char*)d_ws);
  ushort_t* hbuf    = lowb; // alias: lowb consumed before h is written

  if (ws_size < need_base) {
    hipMemsetAsync(d_out, 0, (size_t)out_size * sizeof(float), stream);
    return;
  }
  const bool use_split = (ws_size >= need_full);

  // weight repacks (tiled+swizzled); 9-tap weights via repack9 (36B contiguous reads/lane)
  repack_at_k<<<2048, 256, 0, stream>>>(w_a0, wr_aspp,                     256, 2048, 1, 2, 32);
  repack9_k<<<2048, 256, 0, stream>>>(w_a1, wr_aspp + (size_t)1*524288,  2048, 32);
  repack9_k<<<2048, 256, 0, stream>>>(w_a2, wr_aspp + (size_t)10*524288, 2048, 32);
  repack9_k<<<2048, 256, 0, stream>>>(w_a3, wr_aspp + (size_t)19*524288, 2048, 32);
  if (use_split) repack_xm_k<<<6144,256,0,stream>>>(w_max, wr_aspp + (size_t)28*524288);
  repack_at_k<<<128,  256, 0, stream>>>(w_low,  wr_low,  48,  256,  1, 1, 4);
  repack_at_k<<<1536, 256, 0, stream>>>(w_proj, wr_proj, 256, 1536, 1, 2, 24);
  repack9_k<<<320, 256, 0, stream>>>(w_cls1, wr_cls1, 304, 5);
  id_stats_k<<<1,256,0,stream>>>(stats1536);
  id_stats320_k<<<1,256,0,stream>>>(stats320);

  // layout conversions (f_out conversion also emits pooled partials)
  to_nhwc_k<<<dim3(256,4,8),  256, 0, stream>>>(f_low, lowb, nullptr, nullptr, 256, 16384, 256, 0);
  to_nhwc_k<<<dim3(64,32,8),  256, 0, stream>>>(f_out, xb, use_split ? xb_lo : nullptr, ppart, 2048, 4096, 2048, 1);
  pool_fin_k<<<64,256,0,stream>>>(ppart, pooled);

  // low path: 1x1 conv 256->48 RAW into cls1in[:, :48] (+fused BN partials); BN applied at cls1 B-load
  gemm_conv_at<false><<<dim3(1024,1), 256, 0, stream>>>(wr_low, lowb, cls1in, 48, 1, 4, 256, 320, 7, 14, 128, 1, 1, lowpart, 1024, nullptr);
  bn_fin2_k<<<48,256,0,stream>>>(lowpart, stats320, 2048, 1.f/131072.f);

  // ASPP a0..a3 (+ split-bf16 xm branch) in ONE dispatch, BN partials fused; cat stays RAW
  aspp_conv<<<dim3(256,2,use_split?5:4), 256, 0, stream>>>(wr_aspp, xb, use_split ? xb_lo : xb, cat, xm_raw, catpart, xmpart);
  if (!use_split){
    sgemm_max<<<dim3(64,4,8), 256, 0, stream>>>(w_max, f_out, xm_raw);
    bn_partial_k<float><<<256,256,0,stream>>>(xm_raw, xmpart, 32768, 256, 256);  // [e][c] layout
  }

  // pooled branch r4 (final values; identity slice of stats1536 at proj load)
  r4_k<<<256,256,0,stream>>>(pooled, w_pool, r4b);
  bcast_r4_k<<<4096,256,0,stream>>>(r4b, cat);

  // r0..r3 stats into stats1536[0..1024)
  bn_fin2_k<<<1024,256,0,stream>>>(catpart, stats1536, 512, 1.f/32768.f);

  // xm: stats, fused bn_relu-apply + channel sums
  if (use_split) bn_fin2_k<<<256,256,0,stream>>>(xmpart, statsX, 512, 1.f/32768.f);
  else           bn_fin_k<<<256,256,0,stream>>>(xmpart, statsX, 256, 1.f/32768.f);
  xm_finish_k<<<256,256,0,stream>>>(xm_raw, statsX, xm_bn, partial, 32768);
  chsum_fin_k<<<256,256,0,stream>>>(partial, chs);

  // PSO + selection conv -> cat slice 5 RAW (+fused partials); stats into stats1536[1280..1536)
  pso_k<<<1,64,0,stream>>>(chs, initp, rands, best);
  sel_k<<<4096,256,0,stream>>>(xm_bn, best, w_sel, cat, selpart);
  bn_fin2_k<<<256,256,0,stream>>>(selpart, stats1536 + 1280*2, 4096, 1.f/32768.f);

  // projection 1536->256 with BN+ReLU applied to cat at B-load; output RAW aspp (+fused partials)
  gemm_conv_at<true><<<dim3(256,2), 256, 0, stream>>>(wr_proj, cat, aspp, 256, 2, 24, 1536, 256, 6, 12, 64, 1, 1, projpart, 256, stats1536);
  bn_fin2_k<<<256,256,0,stream>>>(projpart, statsP, 512, 1.f/32768.f);

  // upsample (BN+ReLU fused on sampled aspp values) into cls1in[:, 48:304]
  upsample_k<<<16384,256,0,stream>>>(aspp, statsP, cls1in);

  // cls1 3x3 pad1 304->256 with BN+ReLU on B at load (stats320); output RAW hbuf (+fused partials)
  gemm_conv_at<true><<<dim3(1024,2), 256, 0, stream>>>(wr_cls1, cls1in, hbuf, 256, 2, 5, 320, 256, 7, 14, 128, 9, 1, hpart, 1024, stats320);
  bn_fin2_k<<<256,256,0,stream>>>(hpart, statsH, 2048, 1.f/131072.f);

  // final classifier (BN+ReLU fused on h)
  cls2_k<<<512,256,0,stream>>>(hbuf, statsH, w_cls2, b_cls2, outp);
}

// Round 16
// 1815.522 us; speedup vs baseline: 1.1519x; 1.1519x over previous
//
#include <hip/hip_runtime.h>

typedef __attribute__((ext_vector_type(8))) short bf16x8;
typedef __attribute__((ext_vector_type(4))) float f32x4;
typedef unsigned short ushort_t;
typedef unsigned int uint_t;
typedef __attribute__((address_space(3))) uint_t lds_u32;
typedef const __attribute__((address_space(1))) uint_t glb_u32;

__device__ __forceinline__ float b2f(ushort_t h){ uint_t u = ((uint_t)h)<<16; float f; __builtin_memcpy(&f,&u,4); return f; }
__device__ __forceinline__ ushort_t f2b(float f){ uint_t u; __builtin_memcpy(&u,&f,4); uint_t r = (u + 0x7fffu + ((u>>16)&1u))>>16; return (ushort_t)r; }
__device__ __forceinline__ float as_f(float v){ return v; }
__device__ __forceinline__ float as_f(ushort_t v){ return b2f(v); }
__device__ __forceinline__ int iclamp(int v, int lo, int hi){ return v < lo ? lo : (v > hi ? hi : v); }
__device__ __forceinline__ void gld16(const void* g, void* l){
  __builtin_amdgcn_global_load_lds((glb_u32*)g, (lds_u32*)l, 16, 0, 0);
}

// ---------------- generalized tiled+pre-swizzled weight repack (T=1 weights) ----------------
// layout [t][mb][c][row128][kb64]; stored = w[m=mb*128+row][k=c*64+(kb^((row&7)<<3))][t]; 0-padded
__global__ __launch_bounds__(256) void repack_at_k(const float* __restrict__ w, ushort_t* __restrict__ o,
                                                   int Co, int Ci, int T, int Mb, int Kc){
  long total = (long)T*Mb*Kc*8192;
  long i = (long)blockIdx.x*256 + threadIdx.x;
  if (i >= total) return;
  int e  = (int)(i & 8191);
  long j = i >> 13;
  int c  = (int)(j % Kc); j /= Kc;
  int mb = (int)(j % Mb);
  int t  = (int)(j / Mb);
  int row = e >> 6, kb = e & 63;
  int m = mb*128 + row;
  int k = c*64 + (kb ^ ((row&7)<<3));
  float v = (m < Co && k < Ci) ? w[((size_t)m*Ci + k)*T + t] : 0.f;
  o[i] = f2b(v);
}

// 9-tap repack: one thread handles all 9 taps of one (mb,c,row,kb) slot.
__global__ __launch_bounds__(256) void repack9_k(const float* __restrict__ w, ushort_t* __restrict__ o,
                                                 int Ci, int Kc){
  long total = (long)2*Kc*8192;
  long i = (long)blockIdx.x*256 + threadIdx.x;
  if (i >= total) return;
  int e  = (int)(i & 8191);
  long j = i >> 13;
  int c  = (int)(j % Kc);
  int mb = (int)(j / Kc);
  int row = e >> 6, kb = e & 63;
  int m = mb*128 + row;
  int k = c*64 + (kb ^ ((row&7)<<3));
  size_t tapstride = (size_t)2*Kc*8192;
  if (k < Ci){
    const float* src = w + ((size_t)m*Ci + k)*9;
    #pragma unroll
    for (int t=0;t<9;t++) o[(size_t)t*tapstride + i] = f2b(src[t]);
  } else {
    #pragma unroll
    for (int t=0;t<9;t++) o[(size_t)t*tapstride + i] = 0;
  }
}

// xm split-bf16 weights: taps {hi, hi, lo} of w_max [256][2048]
__global__ __launch_bounds__(256) void repack_xm_k(const float* __restrict__ w, ushort_t* __restrict__ o){
  long i = (long)blockIdx.x*256 + threadIdx.x;
  if (i >= 3l*2*32*8192) return;
  int e  = (int)(i & 8191);
  long j = i >> 13;
  int c  = (int)(j & 31);
  long j2 = j >> 5;
  int mb = (int)(j2 & 1);
  int t  = (int)(j2 >> 1);
  int row = e >> 6, kb = e & 63;
  int m = mb*128 + row;
  int k = c*64 + (kb ^ ((row&7)<<3));
  float v = w[(size_t)m*2048 + k];
  ushort_t hi = f2b(v);
  o[i] = (t < 2) ? hi : f2b(v - b2f(hi));
}

// identity BN slice (for r4 channels 1024..1279 in stats1536)
__global__ void id_stats_k(float* __restrict__ s){
  int c = threadIdx.x;
  s[(1024+c)*2] = 0.f; s[(1024+c)*2+1] = 1.f;
}

// ---------------- NCHW f32 -> NHWC bf16 (tiled transpose; optional lo-part, k-swizzle, pool partials) ----
__global__ __launch_bounds__(256) void to_nhwc_k(const float* __restrict__ in, ushort_t* __restrict__ hi,
                                                 ushort_t* __restrict__ lo, float* __restrict__ ppart,
                                                 int C, int HW, int ldo, int swz){
  __shared__ float t[64][65];
  int p0 = blockIdx.x*64, c0 = blockIdx.y*64, n = blockIdx.z;
  const float* src = in + (size_t)n*C*HW;
  int tp = threadIdx.x & 63, tr = threadIdx.x >> 6;
  #pragma unroll
  for (int i=0;i<16;i++){ int c = tr + i*4; t[c][tp] = src[(size_t)(c0+c)*HW + p0 + tp]; }
  __syncthreads();
  size_t nbase = (size_t)n*HW*ldo;
  float ssum = 0.f;
  #pragma unroll
  for (int i=0;i<16;i++){
    int pr = tr + i*4;
    int p  = p0 + pr;
    int cc = c0 + (swz ? (tp ^ ((p&7)<<3)) : tp);
    float v = t[tp][pr];
    ssum += v;
    ushort_t h = f2b(v);
    hi[nbase + (size_t)p*ldo + cc] = h;
    if (lo) lo[nbase + (size_t)p*ldo + cc] = f2b(v - b2f(h));
  }
  if (ppart){
    __syncthreads();
    t[tr][tp] = ssum;
    __syncthreads();
    if (tr == 0){
      float s = t[0][tp] + t[1][tp] + t[2][tp] + t[3][tp];
      ppart[((size_t)(n*gridDim.x + blockIdx.x))*C + c0 + tp] = s;
    }
  }
}

__global__ __launch_bounds__(256) void pool_fin_k(const float* __restrict__ ppart, float* __restrict__ pooled){
  int gid = blockIdx.x*256 + threadIdx.x;   // 16384 = 8*2048
  int n = gid >> 11, c = gid & 2047;
  float s = 0.f;
  for (int pb=0; pb<64; pb++) s += ppart[((size_t)(n*64 + pb))*2048 + c];
  pooled[gid] = s*(1.f/4096.f);
}

// ---------------- batched ASPP conv: z=0 (1x1), z=1..3 (3x3 d12/24/36), z=4 (xm split-bf16, fp32 out) ----
// Block-uniform zero-tap skip: each 128-pos block spans 2 y-rows; dilated taps fully OOB in y are
// skipped (bit-identical: those taps accumulate exact zeros). Tap-outer (R14 k-outer regressed).
__global__ __launch_bounds__(256, 4) void aspp_conv(const ushort_t* __restrict__ Aall,
                                                 const ushort_t* __restrict__ B,
                                                 const ushort_t* __restrict__ Blo,
                                                 ushort_t* __restrict__ cat,
                                                 float* __restrict__ XM,
                                                 float* __restrict__ catpart,
                                                 float* __restrict__ xmpart){
  __shared__ __align__(16) ushort_t As[128*64];
  __shared__ __align__(16) ushort_t Bs[128*64];
  const int tid = threadIdx.x;
  const int lane = tid & 63, wave = tid >> 6;
  const int wm = (wave>>1)*64, wn = (wave&1)*64;
  const int r = lane & 15, g = lane >> 4;
  const int m0 = blockIdx.y * 128;
  const int xt = blockIdx.x;
  const int p0 = (((xt&7)<<5) | (xt>>3)) << 7;   // XCD-chunked
  const int z  = blockIdx.z;
  const int ntap = (z==0) ? 1 : (z==4 ? 3 : 9);
  const int dil  = (z>=1 && z<=3) ? 12*z : 0;
  const int tap0 = (z==0) ? 0 : (z==4 ? 28 : 1 + 9*(z-1));
  const bool lin = (z==0) || (z==4);
  const int y0blk = (p0 & 4095) >> 6;           // block spans rows y0blk, y0blk+1
  const int srow0 = tid >> 3;
  const int scb16 = (tid & 7) * 16;
  const int swz_s = (srow0 & 7) << 4;

  f32x4 acc[4][4];
  #pragma unroll
  for (int i=0;i<4;i++){
    #pragma unroll
    for (int j=0;j<4;j++){ f32x4 zz = {0.f,0.f,0.f,0.f}; acc[i][j] = zz; }
  }

  for (int t=0; t<ntap; ++t){
    int dy=0, dx=0;
    if (ntap==9){
      dy = (t/3 - 1)*dil; dx = (t%3 - 1)*dil;
      // block-uniform: skip taps whose y-range is entirely OOB (exact-zero contribution)
      if (y0blk + 1 + dy < 0 || y0blk + dy > 63) continue;
    }
    const ushort_t* Bt = (z==4 && t==1) ? Blo : B;
    for (int k0=0; k0<2048; k0+=64){
      const int c = k0 >> 6;
      {
        const char* gA = (const char*)Aall + ((((size_t)(tap0+t)*2 + (m0>>7))*32 + c)<<14) + wave*1024 + lane*16;
        char* lA = (char*)As + wave*1024;
        gld16(gA,          lA);
        gld16(gA +  4096,  lA +  4096);
        gld16(gA +  8192,  lA +  8192);
        gld16(gA + 12288,  lA + 12288);
      }
      if (lin){
        const char* gB = (const char*)Bt + ((size_t)(p0 + wave*8 + (lane>>3))<<12) + (c<<7) + ((lane&7)<<4);
        char* lB = (char*)Bs + wave*1024;
        gld16(gB,                     lB);
        gld16(gB + (size_t)32*4096,   lB +  4096);
        gld16(gB + (size_t)64*4096,   lB +  8192);
        gld16(gB + (size_t)96*4096,   lB + 12288);
      } else {
        #pragma unroll
        for (int i=0;i<4;i+=2){
          uint4 v0{}, v1{};
          #pragma unroll
          for (int u=0;u<2;u++){
            int row = srow0 + (i+u)*32;
            int p = p0 + row;
            int sp = p & 4095;
            int yy = (sp >> 6) + dy, xx = (sp & 63) + dx;
            if ((uint_t)yy < 64u && (uint_t)xx < 64u){
              int q = ((p >> 12) << 12) | (yy << 6) | xx;
              uint4 vv = *(const uint4*)((const char*)B + ((size_t)q<<12) + (c<<7) + (scb16 ^ ((q&7)<<4)));
              if (u==0) v0 = vv; else v1 = vv;
            }
          }
          *(uint4*)((char*)Bs + (srow0+i*32)*128 + (scb16 ^ swz_s)) = v0;
          *(uint4*)((char*)Bs + (srow0+(i+1)*32)*128 + (scb16 ^ swz_s)) = v1;
        }
      }
      __syncthreads();
      #pragma unroll
      for (int ks=0; ks<2; ++ks){
        bf16x8 av[4], bv[4];
        #pragma unroll
        for (int mf=0; mf<4; ++mf){
          int row = wm + mf*16 + r;
          av[mf] = *(const bf16x8*)((const char*)As + row*128 + (((ks*64) + g*16) ^ ((row&7)<<4)));
        }
        #pragma unroll
        for (int nf=0; nf<4; ++nf){
          int row = wn + nf*16 + r;
          bv[nf] = *(const bf16x8*)((const char*)Bs + row*128 + (((ks*64) + g*16) ^ ((row&7)<<4)));
        }
        #pragma unroll
        for (int mf=0; mf<4; ++mf){
          #pragma unroll
          for (int nf=0; nf<4; ++nf)
            acc[mf][nf] = __builtin_amdgcn_mfma_f32_16x16x32_bf16(av[mf], bv[nf], acc[mf][nf], 0,0,0);
        }
      }
      __syncthreads();
    }
  }
  // BN partials from fp32 acc; slot = xt*2 + (wave&1)
  float* part = (z==4) ? xmpart : catpart;
  int cbase = (z==4) ? 0 : z*256;
  int slot = xt*2 + (wave&1);
  #pragma unroll
  for (int mf=0; mf<4; ++mf){
    float ps[4], pss[4];
    #pragma unroll
    for (int j=0;j<4;j++){ ps[j]=0.f; pss[j]=0.f; }
    #pragma unroll
    for (int nf=0; nf<4; ++nf){
      #pragma unroll
      for (int j=0;j<4;j++){ float v = acc[mf][nf][j]; ps[j]+=v; pss[j]+=v*v; }
    }
    #pragma unroll
    for (int o=8;o;o>>=1){
      #pragma unroll
      for (int j=0;j<4;j++){ ps[j]+=__shfl_xor(ps[j],o,16); pss[j]+=__shfl_xor(pss[j],o,16); }
    }
    if (r==0){
      int co = m0 + wm + mf*16 + g*4;
      #pragma unroll
      for (int j=0;j<4;j++){
        size_t idx = ((size_t)(cbase + co + j)*512 + slot)*2;
        part[idx] = ps[j]; part[idx+1] = pss[j];
      }
    }
  }
  if (z == 4){
    #pragma unroll
    for (int mf=0; mf<4; ++mf){
      int co = m0 + wm + mf*16 + g*4;
      #pragma unroll
      for (int nf=0; nf<4; ++nf){
        int pos = p0 + wn + nf*16 + r;
        *(f32x4*)(XM + (size_t)pos*256 + co) = acc[mf][nf];
      }
    }
  } else {
    ushort_t* Cout = cat + z*256;
    #pragma unroll
    for (int mf=0; mf<4; ++mf){
      int co = m0 + wm + mf*16 + g*4;
      #pragma unroll
      for (int nf=0; nf<4; ++nf){
        int pos = p0 + wn + nf*16 + r;
        ushort4 o;
        o.x = f2b(acc[mf][nf][0]); o.y = f2b(acc[mf][nf][1]);
        o.z = f2b(acc[mf][nf][2]); o.w = f2b(acc[mf][nf][3]);
        *(ushort4*)(Cout + (size_t)pos*1536 + co) = o;
      }
    }
  }
}

// ---------------- A-tiled implicit-GEMM conv (async A staging; B natural reg-staged) ----------------
// BN_B: apply per-channel bn_relu to B elements at load time (1-tap/1x1 convs ONLY — on multi-tap
// convs this re-applies BN 9x per element and regressed 250us in R15).
template<bool BN_B>
__global__ __launch_bounds__(256, 4) void gemm_conv_at(const ushort_t* __restrict__ At, const ushort_t* __restrict__ B,
               ushort_t* __restrict__ C,
               int Mvalid, int Mb, int Kc, int ldb, int ldc,
               int logW, int logHW, int H, int ntap, int dil,
               float* __restrict__ bnpart, int gridX, const float* __restrict__ bnB)
{
  __shared__ __align__(16) ushort_t As[128*64];
  __shared__ __align__(16) ushort_t Bs[128*64];
  const int tid = threadIdx.x;
  const int lane = tid & 63, wave = tid >> 6;
  const int wm = (wave>>1)*64, wn = (wave&1)*64;
  const int r = lane & 15, g = lane >> 4;
  const int mb = blockIdx.y;
  const int m0 = mb * 128;
  const int nx = (int)gridDim.x;
  const int xt = (int)blockIdx.x;
  const int p0 = (((nx & 7) == 0) ? ((xt&7)*(nx>>3) + (xt>>3)) : xt) * 128;
  const int W = 1<<logW, HWm1 = (1<<logHW)-1, Wm1 = W-1;
  const int yb0 = (p0 & HWm1) >> logW;
  const int yb1 = ((p0 & HWm1) + 127) >> logW;
  const int srow0 = tid >> 3;
  const int scb16 = (tid & 7) * 16;
  const int swz_s = (srow0 & 7) << 4;

  f32x4 acc[4][4];
  #pragma unroll
  for (int i=0;i<4;i++){
    #pragma unroll
    for (int j=0;j<4;j++){ f32x4 z = {0.f,0.f,0.f,0.f}; acc[i][j] = z; }
  }

  for (int t=0; t<ntap; ++t){
    int dy=0, dx=0;
    if (ntap==9){
      dy = (t/3 - 1)*dil; dx = (t%3 - 1)*dil;
      if (yb1 + dy < 0 || yb0 + dy >= H) continue;   // block-uniform zero-tap skip
    }
    for (int c=0; c<Kc; ++c){
      {
        const char* gA = (const char*)At + ((((size_t)t*Mb + mb)*Kc + c)<<14) + wave*1024 + lane*16;
        char* lA = (char*)As + wave*1024;
        gld16(gA,          lA);
        gld16(gA +  4096,  lA +  4096);
        gld16(gA +  8192,  lA +  8192);
        gld16(gA + 12288,  lA + 12288);
      }
      #pragma unroll
      for (int i=0;i<4;i+=2){
        uint4 v0{}, v1{};
        #pragma unroll
        for (int u=0;u<2;u++){
          int row = srow0 + (i+u)*32;
          int p = p0 + row;
          int sp = p & HWm1;
          int yy = (sp >> logW) + dy, xx = (sp & Wm1) + dx;
          if ((uint_t)yy < (uint_t)H && (uint_t)xx < (uint_t)W){
            int q = ((p >> logHW) << logHW) | (yy << logW) | xx;
            uint4 vv = *(const uint4*)(B + (size_t)q*ldb + (c*64 + (scb16>>1)));
            if constexpr (BN_B){
              union {uint4 q; ushort_t u[8];} uu; uu.q = vv;
              #pragma unroll
              for (int jj=0;jj<8;jj++){
                int ch = c*64 + (scb16>>1) + jj;
                float mm = bnB[ch*2], rr = bnB[ch*2+1];
                uu.u[jj] = f2b(fmaxf((b2f(uu.u[jj])-mm)*rr, 0.f));
              }
              vv = uu.q;
            }
            if (u==0) v0 = vv; else v1 = vv;
          }
        }
        *(uint4*)((char*)Bs + (srow0+i*32)*128 + (scb16 ^ swz_s)) = v0;
        *(uint4*)((char*)Bs + (srow0+(i+1)*32)*128 + (scb16 ^ swz_s)) = v1;
      }
      __syncthreads();
      #pragma unroll
      for (int ks=0; ks<2; ++ks){
        bf16x8 av[4], bv[4];
        #pragma unroll
        for (int mf=0; mf<4; ++mf){
          int row = wm + mf*16 + r;
          av[mf] = *(const bf16x8*)((const char*)As + row*128 + (((ks*64) + g*16) ^ ((row&7)<<4)));
        }
        #pragma unroll
        for (int nf=0; nf<4; ++nf){
          int row = wn + nf*16 + r;
          bv[nf] = *(const bf16x8*)((const char*)Bs + row*128 + (((ks*64) + g*16) ^ ((row&7)<<4)));
        }
        #pragma unroll
        for (int mf=0; mf<4; ++mf){
          #pragma unroll
          for (int nf=0; nf<4; ++nf)
            acc[mf][nf] = __builtin_amdgcn_mfma_f32_16x16x32_bf16(av[mf], bv[nf], acc[mf][nf], 0,0,0);
        }
      }
      __syncthreads();
    }
  }
  if (bnpart){
    int slot = xt*2 + (wave&1);
    #pragma unroll
    for (int mf=0; mf<4; ++mf){
      float ps[4], pss[4];
      #pragma unroll
      for (int j=0;j<4;j++){ ps[j]=0.f; pss[j]=0.f; }
      #pragma unroll
      for (int nf=0; nf<4; ++nf){
        #pragma unroll
        for (int j=0;j<4;j++){ float v = acc[mf][nf][j]; ps[j]+=v; pss[j]+=v*v; }
      }
      #pragma unroll
      for (int o=8;o;o>>=1){
        #pragma unroll
        for (int j=0;j<4;j++){ ps[j]+=__shfl_xor(ps[j],o,16); pss[j]+=__shfl_xor(pss[j],o,16); }
      }
      if (r==0){
        int co = m0 + wm + mf*16 + g*4;
        if (co < Mvalid){
          #pragma unroll
          for (int j=0;j<4;j++){
            size_t idx = ((size_t)(co + j)*(2*gridX) + slot)*2;
            bnpart[idx] = ps[j]; bnpart[idx+1] = pss[j];
          }
        }
      }
    }
  }
  #pragma unroll
  for (int mf=0; mf<4; ++mf){
    int co = m0 + wm + mf*16 + g*4;
    if (co >= Mvalid) continue;
    #pragma unroll
    for (int nf=0; nf<4; ++nf){
      int pos = p0 + wn + nf*16 + r;
      ushort4 o;
      o.x = f2b(acc[mf][nf][0]); o.y = f2b(acc[mf][nf][1]);
      o.z = f2b(acc[mf][nf][2]); o.w = f2b(acc[mf][nf][3]);
      *(ushort4*)(C + (size_t)pos*ldc + co) = o;
    }
  }
}

// ---------------- fp32 SGEMM fallback for w_max conv ----------------
__global__ __launch_bounds__(256) void sgemm_max(const float* __restrict__ Wt, const float* __restrict__ X,
                                                 float* __restrict__ C){
  __shared__ __align__(16) float As[32*68];
  __shared__ __align__(16) float Bs[32*64];
  int tid = threadIdx.x;
  int tx = tid & 15, ty = tid >> 4;
  int p0 = blockIdx.x * 64;
  int m0 = blockIdx.y * 64;
  int n  = blockIdx.z;
  const float* Xb = X + (size_t)n * 2048 * 4096;
  float acc[4][4];
  #pragma unroll
  for (int i=0;i<4;i++){
    #pragma unroll
    for (int j=0;j<4;j++) acc[i][j]=0.f;
  }
  for (int k0=0; k0<2048; k0+=32){
    #pragma unroll
    for (int i=0;i<8;i++){
      int idx = i*256 + tid;
      int mm = idx >> 5, kk = idx & 31;
      As[kk*68 + mm] = Wt[(size_t)(m0+mm)*2048 + k0 + kk];
    }
    #pragma unroll
    for (int i=0;i<8;i++){
      int idx = i*256 + tid;
      int kk = idx >> 6, pp = idx & 63;
      Bs[kk*64 + pp] = Xb[(size_t)(k0+kk)*4096 + p0 + pp];
    }
    __syncthreads();
    #pragma unroll
    for (int kk=0; kk<32; ++kk){
      f32x4 a = *(const f32x4*)&As[kk*68 + ty*4];
      f32x4 b = *(const f32x4*)&Bs[kk*64 + tx*4];
      #pragma unroll
      for (int i=0;i<4;i++){
        #pragma unroll
        for (int j=0;j<4;j++) acc[i][j] += a[i]*b[j];
      }
    }
    __syncthreads();
  }
  #pragma unroll
  for (int j=0;j<4;j++){
    f32x4 o = {acc[0][j], acc[1][j], acc[2][j], acc[3][j]};
    *(f32x4*)(C + (size_t)(n*4096 + p0 + tx*4 + j)*256 + m0 + ty*4) = o;
  }
}

// ---------------- r4: conv_pool + bn_relu over batch, one block per channel ----------------
__global__ __launch_bounds__(256) void r4_k(const float* __restrict__ pooled, const float* __restrict__ wpool,
                                            float* __restrict__ r4b){
  __shared__ float red[8][256];
  int co = blockIdx.x, t = threadIdx.x;
  float y[8];
  #pragma unroll
  for (int n=0;n<8;n++) y[n]=0.f;
  for (int ci=t; ci<2048; ci+=256){
    float wv = wpool[(size_t)co*2048+ci];
    #pragma unroll
    for (int n=0;n<8;n++) y[n] += pooled[n*2048+ci]*wv;
  }
  #pragma unroll
  for (int n=0;n<8;n++) red[n][t] = y[n];
  __syncthreads();
  for (int o=128;o;o>>=1){
    if (t<o){
      #pragma unroll
      for (int n=0;n<8;n++) red[n][t]+=red[n][t+o];
    }
    __syncthreads();
  }
  if (t==0){
    float yv[8], m=0.f;
    #pragma unroll
    for (int n=0;n<8;n++){ yv[n]=red[n][0]; m+=yv[n]; }
    m *= 0.125f;
    float v=0.f;
    #pragma unroll
    for (int n=0;n<8;n++){ float d=yv[n]-m; v+=d*d; }
    v *= 0.125f;
    float rs = rsqrtf(v + 1e-5f);
    #pragma unroll
    for (int n=0;n<8;n++) r4b[n*256+co] = fmaxf((yv[n]-m)*rs, 0.f);
  }
}

__global__ __launch_bounds__(256) void bcast_r4_k(const float* __restrict__ r4b, ushort_t* __restrict__ cat){
  int gid = blockIdx.x*256 + threadIdx.x;
  int pos = gid >> 5, cb = (gid & 31)*8;
  int n = pos >> 12;
  union {uint4 q; ushort_t u[8];} o;
  #pragma unroll
  for (int k=0;k<8;k++) o.u[k] = f2b(r4b[n*256 + cb + k]);
  *(uint4*)(cat + (size_t)pos*1536 + 1024 + cb) = o.q;
}

// ---------------- BN finalize from channel-major partials [C][NBp][2] ----------------
__global__ __launch_bounds__(256) void bn_fin2_k(const float* __restrict__ part, float* __restrict__ stats,
                                                 int NBp, float invN){
  __shared__ float rs_[256], rss_[256];
  int c = blockIdx.x, b = threadIdx.x;
  float s=0.f, ss=0.f;
  for (int e=b; e<NBp; e+=256){
    s  += part[((size_t)c*NBp+e)*2];
    ss += part[((size_t)c*NBp+e)*2+1];
  }
  rs_[b]=s; rss_[b]=ss;
  __syncthreads();
  for (int o=128;o;o>>=1){
    if (b<o){ rs_[b]+=rs_[b+o]; rss_[b]+=rss_[b+o]; }
    __syncthreads();
  }
  if (b==0){
    float m = rs_[0]*invN, var = rss_[0]*invN - m*m;
    stats[c*2]=m; stats[c*2+1]=rsqrtf(fmaxf(var,0.f)+1e-5f);
  }
}

// legacy partial/fin (fallback xm path only)
template<typename TIN>
__global__ __launch_bounds__(256) void bn_partial_k(const TIN* __restrict__ in, float* __restrict__ partial,
                                                    int P, int C, int ld){
  int b = blockIdx.x;
  for (int c = threadIdx.x; c < C; c += 256){
    float s=0.f, ss=0.f;
    for (int p=b; p<P; p+=gridDim.x){ float v = as_f(in[(size_t)p*ld+c]); s+=v; ss+=v*v; }
    partial[((size_t)b*C+c)*2]   = s;
    partial[((size_t)b*C+c)*2+1] = ss;
  }
}
__global__ __launch_bounds__(256) void bn_fin_k(const float* __restrict__ partial, float* __restrict__ stats,
                                                int C, float invN){
  __shared__ float rs_[256], rss_[256];
  int c = blockIdx.x, b = threadIdx.x;
  rs_[b]  = partial[((size_t)b*C+c)*2];
  rss_[b] = partial[((size_t)b*C+c)*2+1];
  __syncthreads();
  for (int o=128;o;o>>=1){
    if (b<o){ rs_[b]+=rs_[b+o]; rss_[b]+=rss_[b+o]; }
    __syncthreads();
  }
  if (b==0){
    float m = rs_[0]*invN, var = rss_[0]*invN - m*m;
    stats[c*2]=m; stats[c*2+1]=rsqrtf(fmaxf(var,0.f)+1e-5f);
  }
}

template<typename TIN>
__global__ __launch_bounds__(256) void bn_apply_k(const TIN* __restrict__ in, ushort_t* __restrict__ out,
                           const float* __restrict__ stats, int total8, int C8, int ldi, int ldo){
  int j = blockIdx.x*256 + threadIdx.x;
  if (j >= total8) return;
  int p = j / C8;
  int c0 = (j - p*C8)*8;
  float v[8];
  if constexpr (sizeof(TIN)==2){
    union { uint4 q; ushort_t u[8]; } ld;
    ld.q = *(const uint4*)((const ushort_t*)in + (size_t)p*ldi + c0);
    #pragma unroll
    for (int k=0;k<8;k++) v[k] = b2f(ld.u[k]);
  } else {
    const f32x4* s = (const f32x4*)((const float*)in + (size_t)p*ldi + c0);
    f32x4 a = s[0], b = s[1];
    #pragma unroll
    for (int k=0;k<4;k++){ v[k]=a[k]; v[k+4]=b[k]; }
  }
  union { ushort_t u[8]; uint4 q; } pk;
  #pragma unroll
  for (int k=0;k<8;k++){
    float m = stats[(c0+k)*2], rs = stats[(c0+k)*2+1];
    pk.u[k] = f2b(fmaxf((v[k]-m)*rs, 0.f));
  }
  *(uint4*)(out + (size_t)p*ldo + c0) = pk.q;
}

// ---------------- fused xm finish: bn_relu apply -> xm_bn (bf16) + channel-sum partials ----------------
__global__ __launch_bounds__(256) void xm_finish_k(const float* __restrict__ xm_raw, const float* __restrict__ stats,
                                                   ushort_t* __restrict__ xm_bn, float* __restrict__ partial, int P){
  int c = threadIdx.x, b = blockIdx.x;
  float m = stats[c*2], rs = stats[c*2+1];
  float s = 0.f;
  for (int p=b; p<P; p+=gridDim.x){
    float v = fmaxf((xm_raw[(size_t)p*256 + c] - m)*rs, 0.f);
    xm_bn[(size_t)p*256 + c] = f2b(v);
    s += v;
  }
  partial[(size_t)b*256 + c] = s;
}

__global__ __launch_bounds__(256) void chsum_fin_k(const float* __restrict__ partial, float* __restrict__ chs){
  __shared__ float r_[256];
  int c = blockIdx.x, b = threadIdx.x;
  r_[b] = partial[(size_t)b*256 + c];
  __syncthreads();
  for (int o=128;o;o>>=1){
    if (b<o) r_[b]+=r_[b+o];
    __syncthreads();
  }
  if (b==0) chs[c] = r_[0];
}

// ---------------- PSO (exact reference semantics, 1 wave, lanes = dims, chs in LDS) ----------------
__global__ void pso_k(const float* __restrict__ chs, const int* __restrict__ initp,
                      const float* __restrict__ rands, int* __restrict__ best){
  __shared__ float cl[256];
  int d = threadIdx.x;
  for (int i=d; i<256; i+=64) cl[i] = chs[i];
  __syncthreads();
  bool act = d < 9;
  float p[9], vel[9], bp[9], bs[9];
  #pragma unroll
  for (int i=0;i<9;i++){
    p[i] = act ? (float)initp[i*9+d] : 0.f;
    vel[i]=0.f; bp[i]=p[i];
  }
  #pragma unroll
  for (int i=0;i<9;i++){
    float s = act ? cl[(int)floorf(p[i])] : 0.f;
    for (int o=8;o;o>>=1) s += __shfl_xor(s,o,16);
    bs[i]=s;
  }
  float gs = bs[0]; int gi=0;
  #pragma unroll
  for (int i=1;i<9;i++) if (bs[i]<gs){gs=bs[i];gi=i;}
  float g = p[0];
  #pragma unroll
  for (int i=1;i<9;i++) if (i==gi) g = p[i];
  for (int it=0; it<100; ++it){
    #pragma unroll
    for (int i=0;i<9;i++){
      float r1 = rands[(it*9+i)*2], r2 = rands[(it*9+i)*2+1];
      float v = 0.7f*vel[i] + 1.5f*r1*(bp[i]-p[i]) + 1.5f*r2*(g-p[i]);
      float pn = fminf(fmaxf(p[i]+v, 0.f), 255.f);
      float fit = act ? cl[(int)floorf(pn)] : 0.f;
      for (int o=8;o;o>>=1) fit += __shfl_xor(fit,o,16);
      bool better = fit < bs[i];
      bp[i] = better ? pn : bp[i];
      bs[i] = better ? fit : bs[i];
      bool gb = fit < gs;
      g  = gb ? pn : g;
      gs = gb ? fit : gs;
      p[i]=pn; vel[i]=v;
    }
  }
  if (act) best[d] = (int)floorf(g);
}

// ---------------- x_sel gather + 1x1 conv (9 -> 256) -> cat slice 5 (+ BN partials) ----------------
__global__ __launch_bounds__(256) void sel_k(const ushort_t* __restrict__ xm_bn, const int* __restrict__ best,
        const float* __restrict__ wsel, ushort_t* __restrict__ cat, float* __restrict__ selpart){
  __shared__ float wl[2304];
  __shared__ float xv[8][9];
  int tid = threadIdx.x;
  for (int i=tid; i<2304; i+=256) wl[i] = wsel[i];
  if (tid < 72){
    int pp = tid/9, jj = tid - pp*9;
    int ch = best[jj];
    xv[pp][jj] = b2f(xm_bn[(size_t)(blockIdx.x*8 + pp)*256 + ch]);
  }
  __syncthreads();
  int co = tid;
  float s = 0.f, ss = 0.f;
  #pragma unroll
  for (int pp=0; pp<8; ++pp){
    float a = 0.f;
    #pragma unroll
    for (int j=0;j<9;j++) a += xv[pp][j]*wl[co*9+j];
    s += a; ss += a*a;
    cat[(size_t)(blockIdx.x*8+pp)*1536 + 1280 + co] = f2b(a);
  }
  size_t idx = ((size_t)co*4096 + blockIdx.x)*2;
  selpart[idx] = s; selpart[idx+1] = ss;
}

// ---------------- bilinear 2x upsample with fused BN+ReLU on sampled values ----------------
__global__ __launch_bounds__(256) void upsample_k(const ushort_t* __restrict__ aspp, const float* __restrict__ stats,
                                                  ushort_t* __restrict__ dst){
  int gid = blockIdx.x*256 + threadIdx.x;
  int pos = gid >> 5, c0 = (gid & 31)*8;
  int n = pos >> 14, sp = pos & 16383;
  int y = sp >> 7, x = sp & 127;
  float sy = y*0.5f - 0.25f, sx = x*0.5f - 0.25f;
  float fy = sy - floorf(sy), fx = sx - floorf(sx);
  int y0 = (int)floorf(sy), x0 = (int)floorf(sx);
  int ya = iclamp(y0,0,63),   yb = iclamp(y0+1,0,63);
  int xa = iclamp(x0,0,63),   xb = iclamp(x0+1,0,63);
  const ushort_t* base = aspp + ((size_t)n<<12)*256;
  float w00=(1.f-fy)*(1.f-fx), w01=(1.f-fy)*fx, w10=fy*(1.f-fx), w11=fy*fx;
  union {uint4 q; ushort_t u[8];} aa, ab, ba, bb, o;
  aa.q = *(const uint4*)(base + (size_t)(ya*64+xa)*256 + c0);
  ab.q = *(const uint4*)(base + (size_t)(ya*64+xb)*256 + c0);
  ba.q = *(const uint4*)(base + (size_t)(yb*64+xa)*256 + c0);
  bb.q = *(const uint4*)(base + (size_t)(yb*64+xb)*256 + c0);
  #pragma unroll
  for (int k=0;k<8;k++){
    float m = stats[(c0+k)*2], rs = stats[(c0+k)*2+1];
    float va = fmaxf((b2f(aa.u[k])-m)*rs, 0.f);
    float vb = fmaxf((b2f(ab.u[k])-m)*rs, 0.f);
    float vc = fmaxf((b2f(ba.u[k])-m)*rs, 0.f);
    float vd = fmaxf((b2f(bb.u[k])-m)*rs, 0.f);
    o.u[k] = f2b(w00*va + w01*vb + w10*vc + w11*vd);
  }
  *(uint4*)(dst + (size_t)pos*320 + 48 + c0) = o.q;
}

// ---------------- final 1x1 conv 256->21 + bias, fused BN+ReLU on h, write NCHW f32 ----------------
__global__ __launch_bounds__(256) void cls2_k(const ushort_t* __restrict__ h, const float* __restrict__ stats,
                                              const float* __restrict__ w,
                                              const float* __restrict__ bias, float* __restrict__ out){
  __shared__ float wl[5376];
  for (int idx=threadIdx.x; idx<5376; idx+=256) wl[idx]=w[idx];
  __syncthreads();
  int pos = blockIdx.x*256 + threadIdx.x;
  int n = pos >> 14, sp = pos & 16383;
  const ushort_t* hr = h + (size_t)pos*256;
  float acc[21];
  #pragma unroll
  for (int co=0;co<21;co++) acc[co]=bias[co];
  for (int k0=0;k0<256;k0+=8){
    union {uint4 q; ushort_t u[8];} ld;
    ld.q = *(const uint4*)(hr + k0);
    float f[8];
    #pragma unroll
    for (int j=0;j<8;j++){
      float m = stats[(k0+j)*2], rs = stats[(k0+j)*2+1];
      f[j] = fmaxf((b2f(ld.u[j])-m)*rs, 0.f);
    }
    #pragma unroll
    for (int co=0;co<21;co++){
      float s=acc[co];
      #pragma unroll
      for (int j=0;j<8;j++) s += f[j]*wl[co*256+k0+j];
      acc[co]=s;
    }
  }
  float* ob = out + (size_t)n*21*16384 + sp;
  #pragma unroll
  for (int co=0;co<21;co++) ob[(size_t)co*16384] = acc[co];
}

extern "C" void kernel_launch(void* const* d_in, const int* in_sizes, int n_in,
                              void* d_out, int out_size, void* d_ws, size_t ws_size,
                              hipStream_t stream) {
  (void)in_sizes; (void)n_in;
  const float* f_out  = (const float*)d_in[0];
  const float* f_low  = (const float*)d_in[1];
  const float* w_low  = (const float*)d_in[2];
  const float* w_a0   = (const float*)d_in[3];
  const float* w_a1   = (const float*)d_in[4];
  const float* w_a2   = (const float*)d_in[5];
  const float* w_a3   = (const float*)d_in[6];
  const float* w_pool = (const float*)d_in[7];
  const float* w_max  = (const float*)d_in[8];
  const float* w_sel  = (const float*)d_in[9];
  const float* w_proj = (const float*)d_in[10];
  const float* w_cls1 = (const float*)d_in[11];
  const float* w_cls2 = (const float*)d_in[12];
  const float* b_cls2 = (const float*)d_in[13];
  const float* rands  = (const float*)d_in[14];
  const int*   initp  = (const int*)d_in[15];
  float* outp = (float*)d_out;

  char* wsp = (char*)d_ws;
  auto alloc = [&](size_t bytes)->char*{ char* p = wsp; wsp += (bytes + 255) & ~(size_t)255; return p; };
  ushort_t* xb      = (ushort_t*)alloc((size_t)8*4096*2048*2);   // feature_out NHWC bf16 (pre-swizzled k)
  ushort_t* lowb    = (ushort_t*)alloc((size_t)131072*256*2);    // feature_low NHWC bf16; later aliased as h
  ushort_t* cls1in  = (ushort_t*)alloc((size_t)131072*320*2);    // [low(48) | up(256) | zpad(16)]
  ushort_t* cat     = (ushort_t*)alloc((size_t)32768*1536*2);    // r0..r5 NHWC (RAW; BN fused into proj load)
  float*    xm_raw  = (float*)alloc((size_t)32768*256*4);
  ushort_t* xm_bn   = (ushort_t*)alloc((size_t)32768*256*2);
  ushort_t* aspp    = (ushort_t*)alloc((size_t)32768*256*2);     // RAW; BN fused into upsample
  ushort_t* wr_aspp = (ushort_t*)alloc((size_t)31*524288*2);     // tiled swizzled: a0|a1[9]|a2[9]|a3[9]|xm[3]
  ushort_t* wr_low  = (ushort_t*)alloc((size_t)1*1*4*8192*2);
  ushort_t* wr_proj = (ushort_t*)alloc((size_t)1*2*24*8192*2);
  ushort_t* wr_cls1 = (ushort_t*)alloc((size_t)9*2*5*8192*2);
  float*    pooled  = (float*)alloc((size_t)16384*4);
  float*    ppart   = (float*)alloc((size_t)8*64*2048*4);
  float*    r4b     = (float*)alloc((size_t)2048*4);
  float*    catpart = (float*)alloc((size_t)1024*512*2*4);
  float*    xmpart  = (float*)alloc((size_t)256*512*2*4);
  float*    hpart   = (float*)alloc((size_t)256*2048*2*4);
  float*    lowpart = (float*)alloc((size_t)128*2048*2*4);
  float*    projpart= (float*)alloc((size_t)256*512*2*4);
  float*    selpart = (float*)alloc((size_t)256*4096*2*4);
  float*    partial = (float*)alloc((size_t)256*256*2*4);
  float*    stats1536=(float*)alloc((size_t)1536*2*4);           // [statsA | id(r4) | statsS]
  float*    statsX  = (float*)alloc((size_t)256*2*4);
  float*    statsP  = (float*)alloc((size_t)256*2*4);
  float*    statsL  = (float*)alloc((size_t)256*2*4);
  float*    statsH  = (float*)alloc((size_t)256*2*4);
  float*    chs     = (float*)alloc((size_t)256*4);
  int*      best    = (int*)alloc(64);
  size_t need_base = (size_t)(wsp - (char*)d_ws);
  ushort_t* xb_lo   = (ushort_t*)alloc((size_t)8*4096*2048*2);   // lo part for split-bf16 xm
  size_t need_full = (size_t)(wsp - (char*)d_ws);
  ushort_t* hbuf    = lowb; // alias: lowb consumed before h is written

  if (ws_size < need_base) {
    hipMemsetAsync(d_out, 0, (size_t)out_size * sizeof(float), stream);
    return;
  }
  const bool use_split = (ws_size >= need_full);

  // weight repacks (tiled+swizzled); 9-tap weights via repack9 (36B contiguous reads/lane)
  repack_at_k<<<2048, 256, 0, stream>>>(w_a0, wr_aspp,                     256, 2048, 1, 2, 32);
  repack9_k<<<2048, 256, 0, stream>>>(w_a1, wr_aspp + (size_t)1*524288,  2048, 32);
  repack9_k<<<2048, 256, 0, stream>>>(w_a2, wr_aspp + (size_t)10*524288, 2048, 32);
  repack9_k<<<2048, 256, 0, stream>>>(w_a3, wr_aspp + (size_t)19*524288, 2048, 32);
  if (use_split) repack_xm_k<<<6144,256,0,stream>>>(w_max, wr_aspp + (size_t)28*524288);
  repack_at_k<<<128,  256, 0, stream>>>(w_low,  wr_low,  48,  256,  1, 1, 4);
  repack_at_k<<<1536, 256, 0, stream>>>(w_proj, wr_proj, 256, 1536, 1, 2, 24);
  repack9_k<<<320, 256, 0, stream>>>(w_cls1, wr_cls1, 304, 5);
  id_stats_k<<<1,256,0,stream>>>(stats1536);

  // layout conversions (f_out conversion also emits pooled partials)
  to_nhwc_k<<<dim3(256,4,8),  256, 0, stream>>>(f_low, lowb, nullptr, nullptr, 256, 16384, 256, 0);
  to_nhwc_k<<<dim3(64,32,8),  256, 0, stream>>>(f_out, xb, use_split ? xb_lo : nullptr, ppart, 2048, 4096, 2048, 1);
  pool_fin_k<<<64,256,0,stream>>>(ppart, pooled);

  // low path: 1x1 conv 256->48 (+fused BN partials) + bn_relu, into cls1in[:, :48]
  gemm_conv_at<false><<<dim3(1024,1), 256, 0, stream>>>(wr_low, lowb, cls1in, 48, 1, 4, 256, 320, 7, 14, 128, 1, 1, lowpart, 1024, nullptr);
  bn_fin2_k<<<48,256,0,stream>>>(lowpart, statsL, 2048, 1.f/131072.f);
  bn_apply_k<ushort_t><<<3072,256,0,stream>>>(cls1in, cls1in, statsL, 786432, 6, 320, 320);

  // ASPP a0..a3 (+ split-bf16 xm branch) in ONE dispatch, BN partials fused; cat stays RAW
  aspp_conv<<<dim3(256,2,use_split?5:4), 256, 0, stream>>>(wr_aspp, xb, use_split ? xb_lo : xb, cat, xm_raw, catpart, xmpart);
  if (!use_split){
    sgemm_max<<<dim3(64,4,8), 256, 0, stream>>>(w_max, f_out, xm_raw);
    bn_partial_k<float><<<256,256,0,stream>>>(xm_raw, xmpart, 32768, 256, 256);  // [e][c] layout
  }

  // pooled branch r4 (final values; identity slice of stats1536 at proj load)
  r4_k<<<256,256,0,stream>>>(pooled, w_pool, r4b);
  bcast_r4_k<<<4096,256,0,stream>>>(r4b, cat);

  // r0..r3 stats into stats1536[0..1024)
  bn_fin2_k<<<1024,256,0,stream>>>(catpart, stats1536, 512, 1.f/32768.f);

  // xm: stats, fused bn_relu-apply + channel sums
  if (use_split) bn_fin2_k<<<256,256,0,stream>>>(xmpart, statsX, 512, 1.f/32768.f);
  else           bn_fin_k<<<256,256,0,stream>>>(xmpart, statsX, 256, 1.f/32768.f);
  xm_finish_k<<<256,256,0,stream>>>(xm_raw, statsX, xm_bn, partial, 32768);
  chsum_fin_k<<<256,256,0,stream>>>(partial, chs);

  // PSO + selection conv -> cat slice 5 RAW (+fused partials); stats into stats1536[1280..1536)
  pso_k<<<1,64,0,stream>>>(chs, initp, rands, best);
  sel_k<<<4096,256,0,stream>>>(xm_bn, best, w_sel, cat, selpart);
  bn_fin2_k<<<256,256,0,stream>>>(selpart, stats1536 + 1280*2, 4096, 1.f/32768.f);

  // projection 1536->256 with BN+ReLU applied to cat at B-load; output RAW aspp (+fused partials)
  gemm_conv_at<true><<<dim3(256,2), 256, 0, stream>>>(wr_proj, cat, aspp, 256, 2, 24, 1536, 256, 6, 12, 64, 1, 1, projpart, 256, stats1536);
  bn_fin2_k<<<256,256,0,stream>>>(projpart, statsP, 512, 1.f/32768.f);

  // upsample (BN+ReLU fused on sampled aspp values) into cls1in[:, 48:304]
  upsample_k<<<16384,256,0,stream>>>(aspp, statsP, cls1in);

  // cls1 3x3 pad1 304->256 (+fused partials); output RAW hbuf
  gemm_conv_at<false><<<dim3(1024,2), 256, 0, stream>>>(wr_cls1, cls1in, hbuf, 256, 2, 5, 320, 256, 7, 14, 128, 9, 1, hpart, 1024, nullptr);
  bn_fin2_k<<<256,256,0,stream>>>(hpart, statsH, 2048, 1.f/131072.f);

  // final classifier (BN+ReLU fused on h)
  cls2_k<<<512,256,0,stream>>>(hbuf, statsH, w_cls2, b_cls2, outp);
}